// Round 1
// baseline (1836.399 us; speedup 1.0000x reference)
//
#include <hip/hip_runtime.h>
#include <hip/hip_bf16.h>

// Problem constants (match reference)
#define B_   32
#define C_   128
#define H_   56
#define W_   56
#define KSEL 2
#define E_   8
#define KN_  128
// KS=3, PAD=1

// ---------------------------------------------------------------------------
// Kernel 1: fuse the 1x1 channel-mix into the 3x3 conv weights.
//   Weff[e][o][c][j] = sum_k Wch[e][o][C_+k] * Ws[e][k][c][j]   (j = dy*3+dx)
//   Weff[e][o][c][4] += Wch[e][o][c]                            (identity path)
// grid = E_*C_ blocks (one per (e,c)), block = 128 threads (one per o).
// ---------------------------------------------------------------------------
__global__ __launch_bounds__(128) void fuse_weights_kernel(
    const float* __restrict__ Ws,    // [E][KN][C][3][3]
    const float* __restrict__ Wch,   // [E][C][C+KN]
    float* __restrict__ Weff) {      // [E][KN][C][9]
  const int e = blockIdx.x >> 7;     // / C_
  const int c = blockIdx.x & 127;    // % C_
  const int o = threadIdx.x;

  __shared__ float sWs[KN_][9];      // Ws[e][k][c][:] for all k
  for (int l = threadIdx.x; l < KN_ * 9; l += 128) {
    int k = l / 9, j = l % 9;
    sWs[k][j] = Ws[((size_t)(e * KN_ + k) * C_ + c) * 9 + j];
  }
  __syncthreads();

  float acc[9];
#pragma unroll
  for (int j = 0; j < 9; ++j) acc[j] = 0.f;

  const float* wrow = Wch + (size_t)(e * C_ + o) * (C_ + KN_) + C_;  // [KN]
  for (int k = 0; k < KN_; k += 4) {
    const float4 wv = *(const float4*)(wrow + k);
#pragma unroll
    for (int j = 0; j < 9; ++j) {
      acc[j] += wv.x * sWs[k + 0][j];
      acc[j] += wv.y * sWs[k + 1][j];
      acc[j] += wv.z * sWs[k + 2][j];
      acc[j] += wv.w * sWs[k + 3][j];
    }
  }
  // identity path: x contributes at the center tap (dy=1,dx=1 -> j=4)
  acc[4] += Wch[(size_t)(e * C_ + o) * (C_ + KN_) + c];

  float* dst = Weff + ((size_t)(e * KN_ + o) * C_ + c) * 9;
#pragma unroll
  for (int j = 0; j < 9; ++j) dst[j] = acc[j];
}

// ---------------------------------------------------------------------------
// Kernel 2: direct 3x3 conv with fused weights.
// Block = one (b,g) x 16-out-channel tile x 8x8 spatial tile.
// 256 threads = 64 spatial (8x8) x 4 channel-groups; each thread accumulates
// 4 consecutive output channels (float4 weight broadcast per wave).
// grid = (B*KSEL) * (KN/16) * (7*7) = 64 * 8 * 49 = 25088 blocks.
// ---------------------------------------------------------------------------
__global__ __launch_bounds__(256) void conv_fused_kernel(
    const float* __restrict__ x,     // [B][C][H][W]
    const int* __restrict__ gate,    // [B][KSEL]
    const float* __restrict__ Weff,  // [E][KN][C][9]
    float* __restrict__ out) {       // [B][KSEL][C][H][W]
  const int blk = blockIdx.x;
  const int t  = blk % 49;
  const int ob = (blk / 49) & 7;     // output-channel block (16 channels)
  const int bg = blk / (49 * 8);     // 0..63
  const int b = bg >> 1, g = bg & 1;
  const int e = gate[b * KSEL + g];
  const int h0 = (t / 7) * 8, w0 = (t % 7) * 8;

  const int tid = threadIdx.x;
  const int sp = tid & 63;           // spatial lane within wave
  const int og = tid >> 6;           // which group of 4 output channels (wave id)
  const int sy = sp >> 3, sx = sp & 7;

  __shared__ __align__(16) float sX[4][10][10];   // 4 in-channels, 10x10 halo tile
  __shared__ __align__(16) float sW[4][9][16];    // [c][j][16 out-ch]

  float acc[4] = {0.f, 0.f, 0.f, 0.f};

  const float* xb = x + (size_t)b * C_ * H_ * W_;
  const float* wb = Weff + ((size_t)e * KN_ + ob * 16) * C_ * 9;

  for (int c0 = 0; c0 < C_; c0 += 4) {
    __syncthreads();
    // stage x tile: 4 channels x 10x10 (with zero halo)
    for (int l = tid; l < 400; l += 256) {
      int c = l / 100, r = l % 100;
      int y = r / 10, xx = r % 10;
      int gy = h0 + y - 1, gx = w0 + xx - 1;
      float v = 0.f;
      if (gy >= 0 && gy < H_ && gx >= 0 && gx < W_)
        v = xb[(size_t)(c0 + c) * (H_ * W_) + gy * W_ + gx];
      (&sX[0][0][0])[l] = v;
    }
    // stage weights: sW[c][j][i] = Weff[e][ob*16+i][c0+c][j]
    for (int l = tid; l < 576; l += 256) {
      int i = l & 15;
      int j = (l >> 4) % 9;
      int c = l / 144;
      (&sW[0][0][0])[l] = wb[((size_t)i * C_ + c0 + c) * 9 + j];
    }
    __syncthreads();

#pragma unroll
    for (int c = 0; c < 4; ++c) {
#pragma unroll
      for (int j = 0; j < 9; ++j) {
        const int dy = j / 3, dx = j % 3;
        const float xv = sX[c][sy + dy][sx + dx];
        const float4 wv = *(const float4*)&sW[c][j][og * 4];  // wave-broadcast
        acc[0] += wv.x * xv;
        acc[1] += wv.y * xv;
        acc[2] += wv.z * xv;
        acc[3] += wv.w * xv;
      }
    }
  }

  // out[b][g][o][h][w], o = ob*16 + og*4 + u
  float* op = out + ((size_t)(b * KSEL + g) * C_ + ob * 16 + og * 4) * (H_ * W_)
            + (h0 + sy) * W_ + (w0 + sx);
#pragma unroll
  for (int u = 0; u < 4; ++u) op[(size_t)u * H_ * W_] = acc[u];
}

extern "C" void kernel_launch(void* const* d_in, const int* in_sizes, int n_in,
                              void* d_out, int out_size, void* d_ws, size_t ws_size,
                              hipStream_t stream) {
  const float* x    = (const float*)d_in[0];   // [32,128,56,56]
  const int*   gate = (const int*)d_in[1];     // [32,2]
  const float* Ws   = (const float*)d_in[2];   // [8,128,128,3,3]
  const float* Wch  = (const float*)d_in[3];   // [8,128,256,1,1]
  float* out = (float*)d_out;                  // [32,2,128,56,56]

  float* Weff = (float*)d_ws;                  // [8][128][128][9] = 4.7 MB

  fuse_weights_kernel<<<E_ * C_, 128, 0, stream>>>(Ws, Wch, Weff);

  const int nblocks = (B_ * KSEL) * (KN_ / 16) * 49;  // 25088
  conv_fused_kernel<<<nblocks, 256, 0, stream>>>(x, gate, Weff, out);
}

// Round 3
// 328.889 us; speedup vs baseline: 5.5836x; 5.5836x over previous
//
#include <hip/hip_runtime.h>
#include <hip/hip_bf16.h>

// Problem constants (match reference)
#define B_   32
#define C_   128
#define H_   56
#define W_   56
#define KSEL 2
#define E_   8
#define KN_  128
// KS=3, PAD=1

typedef __attribute__((ext_vector_type(8))) short short8;   // 8 x bf16 (4 VGPRs)
typedef __attribute__((ext_vector_type(4))) float f32x4;    // MFMA accumulator

static __device__ __forceinline__ ushort f2bf(float f) {
  union { float f; uint u; } v; v.f = f;
  uint u = v.u;
  return (ushort)((u + 0x7fffu + ((u >> 16) & 1u)) >> 16);  // RNE
}

// ---------------------------------------------------------------------------
// Kernel 1: fuse 1x1 channel-mix into the 3x3 conv weights, emit bf16.
//   Weff[e][j][o][c] = sum_k Wch[e][o][C_+k] * Ws[e][k][c][j]
//   Weff[e][4][o][c] += Wch[e][o][c]        (identity path = center tap)
// Layout [e][j][o][c]: c contiguous -> MFMA B-operand loads are ds_read_b128.
// grid = E_*C_ blocks (one per (e,c)), block = 128 threads (one per o).
// ---------------------------------------------------------------------------
__global__ __launch_bounds__(128) void fuse_weights_kernel(
    const float* __restrict__ Ws,    // [E][KN][C][3][3]
    const float* __restrict__ Wch,   // [E][C][C+KN]
    ushort* __restrict__ Weff) {     // [E][9][KN][C] bf16
  const int e = blockIdx.x >> 7;
  const int c = blockIdx.x & 127;
  const int o = threadIdx.x;

  __shared__ float sWs[KN_][9];
  for (int l = threadIdx.x; l < KN_ * 9; l += 128) {
    int k = l / 9, j = l % 9;
    sWs[k][j] = Ws[((size_t)(e * KN_ + k) * C_ + c) * 9 + j];
  }
  __syncthreads();

  float acc[9];
#pragma unroll
  for (int j = 0; j < 9; ++j) acc[j] = 0.f;

  const float* wrow = Wch + (size_t)(e * C_ + o) * (C_ + KN_) + C_;
  for (int k = 0; k < KN_; k += 4) {
    const float4 wv = *(const float4*)(wrow + k);
#pragma unroll
    for (int j = 0; j < 9; ++j) {
      acc[j] += wv.x * sWs[k + 0][j];
      acc[j] += wv.y * sWs[k + 1][j];
      acc[j] += wv.z * sWs[k + 2][j];
      acc[j] += wv.w * sWs[k + 3][j];
    }
  }
  acc[4] += Wch[(size_t)(e * C_ + o) * (C_ + KN_) + c];

#pragma unroll
  for (int j = 0; j < 9; ++j)
    Weff[((size_t)(e * 9 + j) * KN_ + o) * C_ + c] = f2bf(acc[j]);
}

// ---------------------------------------------------------------------------
// Kernel 2: implicit-GEMM MFMA conv.
// Block = (b,g) x 2 output rows. M = 112 spatial (7 m-tiles), N = 128 out-ch
// (8 n-tiles), K = 9 taps x 128 c. 4 waves; wave handles 7m x 2n fragments.
// sX: [4 rows][58 cols][32 c] bf16 (stride padded 32->40 ushorts, 80 B).
//     col index = gw+1 (gw = -1..56); conv for output w reads cols w+dx.
// sW: [3 dx][128 o][32 c] bf16 (same padding).
// ---------------------------------------------------------------------------
#define XSTR 40   // ushorts per (row,col) cell; 32 used, padded for banks
#define WSTR 40   // ushorts per o-row; 32 used

__global__ __launch_bounds__(256) void conv_mfma_kernel(
    const float* __restrict__ x,     // [B][C][H][W] fp32
    const int* __restrict__ gate,    // [B][KSEL]
    const ushort* __restrict__ Weff, // [E][9][KN][C] bf16
    float* __restrict__ out) {       // [B][KSEL][C][H][W] fp32
  const int tileh = blockIdx.x;      // 0..27 (2 rows each)
  const int bg    = blockIdx.y;      // 0..63 = b*2+g
  const int b  = bg >> 1;
  const int h0 = tileh * 2;
  const int e  = gate[bg];

  const int tid = threadIdx.x;
  const int wv = tid >> 6, lane = tid & 63;
  const int l15 = lane & 15, kq = lane >> 4;
  const int obase = wv * 32;

  __shared__ __align__(16) ushort sX[4 * 58 * XSTR];   // 18560 B
  __shared__ __align__(16) ushort sW[3 * 128 * WSTR];  // 30720 B

  f32x4 acc[7][2];
#pragma unroll
  for (int t = 0; t < 7; ++t) {
    acc[t][0] = (f32x4){0.f, 0.f, 0.f, 0.f};
    acc[t][1] = (f32x4){0.f, 0.f, 0.f, 0.f};
  }

  // A-fragment LDS offsets (ushort units). Output position p=(r,w);
  // compute adds (dy*58+dx)*XSTR, giving row r+dy, col w+dx (gw=w-1+dx). 
  int xoff[7];
#pragma unroll
  for (int t = 0; t < 7; ++t) {
    int p = t * 16 + l15;
    int r = (p >= 56) ? 1 : 0;
    int w = p - r * 56;
    xoff[t] = (r * 58 + w) * XSTR + kq * 8;
  }
  const int woffA = (obase + l15) * WSTR + kq * 8;
  const int woffB = woffA + 16 * WSTR;

  const float*  xb = x + (size_t)b * C_ * H_ * W_;
  const ushort* wb = Weff + (size_t)e * 9 * KN_ * C_;

  for (int cc = 0; cc < 4; ++cc) {
    const int c0 = cc * 32;
    __syncthreads();  // protect previous round's sX reads
    // ---- stage sX: rows h0-1..h0+2, cols gw=-1..56, 32 channels (bf16 pairs)
    for (int l = tid; l < 4 * 58 * 16; l += 256) {
      int col = l % 58;
      int cp  = (l / 58) & 15;
      int row = l / (58 * 16);
      int gh = h0 - 1 + row, gw = col - 1;
      uint val = 0u;
      if (gh >= 0 && gh < H_ && gw >= 0 && gw < W_) {
        const float* s = xb + ((size_t)(c0 + 2 * cp) * H_ + gh) * W_ + gw;
        val = (uint)f2bf(s[0]) | ((uint)f2bf(s[H_ * W_]) << 16);
      }
      ((uint*)sX)[(row * 58 + col) * (XSTR / 2) + cp] = val;
    }
    for (int dy = 0; dy < 3; ++dy) {
      __syncthreads();  // protect previous sW reads (+ sX writes on dy==0)
      // ---- stage sW: taps j = dy*3 + {0,1,2}, 128 o x 32 c
      for (int l = tid; l < 3 * 128 * 16; l += 256) {
        int cp = l & 15;
        int o  = (l >> 4) & 127;
        int dx = l >> 11;
        uint v = *(const uint*)(wb + ((size_t)((dy * 3 + dx) * KN_ + o) * C_) + c0 + 2 * cp);
        ((uint*)sW)[(dx * 128 + o) * (WSTR / 2) + cp] = v;
      }
      __syncthreads();
      // ---- compute: 3 dx x 7 m-tiles x 2 n-tiles
#pragma unroll
      for (int dx = 0; dx < 3; ++dx) {
        short8 b0 = *(const short8*)&sW[woffA + dx * 128 * WSTR];
        short8 b1 = *(const short8*)&sW[woffB + dx * 128 * WSTR];
        const int ao = (dy * 58 + dx) * XSTR;
#pragma unroll
        for (int t = 0; t < 7; ++t) {
          short8 a = *(const short8*)&sX[xoff[t] + ao];
          acc[t][0] = __builtin_amdgcn_mfma_f32_16x16x32_bf16(a, b0, acc[t][0], 0, 0, 0);
          acc[t][1] = __builtin_amdgcn_mfma_f32_16x16x32_bf16(a, b1, acc[t][1], 0, 0, 0);
        }
      }
    }
  }

  // ---- epilogue: lane holds rows p = t*16 + kq*4 + reg, col o = obase+i*16+l15
#pragma unroll
  for (int t = 0; t < 7; ++t) {
    int p0 = t * 16 + kq * 4;
    int r  = (p0 >= 56) ? 1 : 0;
    int w0 = p0 - r * 56;
    int h  = h0 + r;
#pragma unroll
    for (int i = 0; i < 2; ++i) {
      float* op = out + (((size_t)bg * C_ + obase + i * 16 + l15) * H_ + h) * W_ + w0;
      *(float4*)op = make_float4(acc[t][i][0], acc[t][i][1], acc[t][i][2], acc[t][i][3]);
    }
  }
}

extern "C" void kernel_launch(void* const* d_in, const int* in_sizes, int n_in,
                              void* d_out, int out_size, void* d_ws, size_t ws_size,
                              hipStream_t stream) {
  const float* x    = (const float*)d_in[0];   // [32,128,56,56]
  const int*   gate = (const int*)d_in[1];     // [32,2]
  const float* Ws   = (const float*)d_in[2];   // [8,128,128,3,3]
  const float* Wch  = (const float*)d_in[3];   // [8,128,256,1,1]
  float* out = (float*)d_out;                  // [32,2,128,56,56]

  ushort* Weff = (ushort*)d_ws;                // [8][9][128][128] bf16 = 2.36 MB

  fuse_weights_kernel<<<E_ * C_, 128, 0, stream>>>(Ws, Wch, Weff);

  dim3 grid(28, 64);
  conv_mfma_kernel<<<grid, 256, 0, stream>>>(x, gate, Weff, out);
}

// Round 5
// 251.445 us; speedup vs baseline: 7.3034x; 1.3080x over previous
//
#include <hip/hip_runtime.h>
#include <hip/hip_bf16.h>

// Problem constants
#define B_   32
#define C_   128
#define H_   56
#define W_   56
#define KSEL 2
#define E_   8
#define KN_  128
// KS=3, PAD=1

typedef __attribute__((ext_vector_type(8))) short short8;   // 8 x bf16
typedef __attribute__((ext_vector_type(4))) float f32x4;    // MFMA accumulator

static __device__ __forceinline__ ushort f2bf(float f) {
  union { float f; uint u; } v; v.f = f;
  uint u = v.u;
  return (ushort)((u + 0x7fffu + ((u >> 16) & 1u)) >> 16);  // RNE
}

// ---------------------------------------------------------------------------
// Kernel 0: x fp32 NCHW -> bf16 NHWC with zero halo baked in.
//   xh[b][h'][w'][c], h',w' in [0,58); h=h'-1, w=w'-1; border cells zero.
// grid = (58, 32) blocks x 256 threads. Transpose via LDS.
// ---------------------------------------------------------------------------
__global__ __launch_bounds__(256) void prep_x_kernel(
    const float* __restrict__ x, ushort* __restrict__ xh) {
  const int hp = blockIdx.x;   // 0..57
  const int b  = blockIdx.y;
  const int tid = threadIdx.x;
  ushort* rowp = xh + (size_t)(b * 58 + hp) * 58 * 128;

  if (hp == 0 || hp == 57) {            // zero halo rows
    uint4 z = make_uint4(0, 0, 0, 0);
    for (int l = tid; l < 464; l += 256) ((uint4*)rowp)[l] = z;
    return;
  }
  const int h = hp - 1;
  __shared__ __align__(16) ushort sT[56 * 136];   // [w][c], c-stride padded

  const float* xb = x + (size_t)b * C_ * H_ * W_ + h * W_;
#pragma unroll
  for (int it = 0; it < 7; ++it) {
    int i4 = tid + it * 256;            // 0..1791
    int c  = i4 / 14;
    int w4 = (i4 - c * 14) * 4;
    float4 v = *(const float4*)(xb + (size_t)c * (H_ * W_) + w4);
    sT[(w4 + 0) * 136 + c] = f2bf(v.x);
    sT[(w4 + 1) * 136 + c] = f2bf(v.y);
    sT[(w4 + 2) * 136 + c] = f2bf(v.z);
    sT[(w4 + 3) * 136 + c] = f2bf(v.w);
  }
  __syncthreads();
  for (int l = tid; l < 896; l += 256) {   // cells w'=1..56
    int w = l >> 4, sub = l & 15;
    uint4 v = *(const uint4*)&sT[w * 136 + sub * 8];
    *(uint4*)(rowp + (size_t)(w + 1) * 128 + sub * 8) = v;
  }
  if (tid < 32) {                           // halo cells w'=0,57
    int wp = (tid < 16) ? 0 : 57;
    uint4 z = make_uint4(0, 0, 0, 0);
    *(uint4*)(rowp + (size_t)wp * 128 + (tid & 15) * 8) = z;
  }
}

// ---------------------------------------------------------------------------
// Kernel 1: fuse 1x1 mix into 3x3 weights (fp32 tiled GEMM), emit bf16.
//   Weff[e][j][o][c] = sum_k Wch[e][o][C_+k] * Ws[e][k][c][j]; +Wch[e][o][c] at j=4
// grid = (8 e, 4 o-tiles, 4 c-tiles) x 256 threads.
// Thread: o = o0 + tid/8, c = c0 + (tid%8)*4 .. +3; acc[9][4].
// ---------------------------------------------------------------------------
__global__ __launch_bounds__(256) void fuse_weights_kernel(
    const float* __restrict__ Ws,    // [E][KN][C][9]
    const float* __restrict__ Wch,   // [E][C][256]
    ushort* __restrict__ Weff) {     // [E][9][KN][C] bf16
  const int e  = blockIdx.x;
  const int o0 = blockIdx.y * 32;
  const int c0 = blockIdx.z * 32;
  const int tid = threadIdx.x;
  const int ol = tid >> 3;           // 0..31
  const int cq = (tid & 7) * 4;      // 0..28

  __shared__ __align__(16) float sA[32 * 129];       // Wch gate part [o][k]
  __shared__ __align__(16) float sB[32 * 32 * 12];   // Ws chunk [k][c][12]

  // stage sA (whole K=128): 32 o-rows x 32 float4 chunks (128 k each)
#pragma unroll
  for (int it = 0; it < 4; ++it) {
    int i4 = tid + it * 256;         // 0..1023
    int o  = i4 >> 5;                // 0..31
    int kk = (i4 & 31) * 4;          // 0..124
    float4 v = *(const float4*)(Wch + (size_t)(e * C_ + o0 + o) * 256 + 128 + kk);
    sA[o * 129 + kk + 0] = v.x;
    sA[o * 129 + kk + 1] = v.y;
    sA[o * 129 + kk + 2] = v.z;
    sA[o * 129 + kk + 3] = v.w;
  }

  float acc[9][4];
#pragma unroll
  for (int j = 0; j < 9; ++j)
#pragma unroll
    for (int c2 = 0; c2 < 4; ++c2) acc[j][c2] = 0.f;

  for (int k0 = 0; k0 < 128; k0 += 32) {
    __syncthreads();
    {  // stage sB: 32 k-rows, each 288 contiguous floats (32c x 9j), repack [k][c][12]
      int k = tid >> 3, seg = tid & 7;
      const float* src = Ws + ((size_t)(e * KN_ + k0 + k) * C_ + c0) * 9 + seg * 36;
      float vb[36];
#pragma unroll
      for (int q = 0; q < 9; ++q) {
        float4 v = *(const float4*)(src + q * 4);
        vb[q * 4 + 0] = v.x; vb[q * 4 + 1] = v.y;
        vb[q * 4 + 2] = v.z; vb[q * 4 + 3] = v.w;
      }
      int c = seg * 4, j = 0;   // seg*36 = (seg*4)*9 exactly
#pragma unroll
      for (int m = 0; m < 36; ++m) {
        sB[(k * 32 + c) * 12 + j] = vb[m];
        if (++j == 9) { j = 0; ++c; }
      }
    }
    __syncthreads();
    for (int k = 0; k < 32; ++k) {
      float a = sA[ol * 129 + k0 + k];
#pragma unroll
      for (int c2 = 0; c2 < 4; ++c2) {
        const float* bp = &sB[(k * 32 + cq + c2) * 12];
#pragma unroll
        for (int j = 0; j < 9; ++j) acc[j][c2] += a * bp[j];
      }
    }
  }

  const int o = o0 + ol;
#pragma unroll
  for (int c2 = 0; c2 < 4; ++c2)
    acc[4][c2] += Wch[(size_t)(e * C_ + o) * 256 + c0 + cq + c2];
#pragma unroll
  for (int j = 0; j < 9; ++j) {
    uint lo = (uint)f2bf(acc[j][0]) | ((uint)f2bf(acc[j][1]) << 16);
    uint hi = (uint)f2bf(acc[j][2]) | ((uint)f2bf(acc[j][3]) << 16);
    uint2* dst = (uint2*)(Weff + ((size_t)((e * 9 + j) * KN_ + o)) * C_ + c0 + cq);
    *dst = make_uint2(lo, hi);
  }
}

// ---------------------------------------------------------------------------
// Kernel 2: implicit-GEMM MFMA conv from bf16 NHWC-halo x.
// Block = (b,g) x 4 output rows: M=224 (14 m-tiles), N=128 (8 n-tiles), K=1152.
// 4 waves: wave (mh,nh) covers 7 m-tiles x 4 n-tiles; acc 7x4 f32x4.
// sX: [6 rows][58 cols][32c] bf16, cell stride padded to 40 ushorts.
// sW: [3 dx][128 o][32c] bf16, same padding; restaged per (cc,dy).
// ---------------------------------------------------------------------------
#define XSTR 40
#define WSTR 40

__global__ __launch_bounds__(256, 2) void conv_mfma_kernel(
    const ushort* __restrict__ xh,   // [B][58][58][128] bf16
    const int* __restrict__ gate,    // [B][KSEL]
    const ushort* __restrict__ Weff, // [E][9][KN][C] bf16
    float* __restrict__ out) {       // [B][KSEL][C][H][W] fp32
  const int ht = blockIdx.x;         // 0..13 (4 rows each)
  const int bg = blockIdx.y;         // 0..63
  const int b  = bg >> 1;
  const int h0 = ht * 4;
  const int e  = gate[bg];

  const int tid = threadIdx.x;
  const int wv = tid >> 6, lane = tid & 63;
  const int l15 = lane & 15, kq = lane >> 4;
  const int mh = wv >> 1, nh = wv & 1;

  __shared__ __align__(16) ushort sX[6 * 58 * XSTR];   // 27840 B
  __shared__ __align__(16) ushort sW[3 * 128 * WSTR];  // 30720 B

  f32x4 acc[7][4];
#pragma unroll
  for (int t = 0; t < 7; ++t)
#pragma unroll
    for (int i = 0; i < 4; ++i) acc[t][i] = (f32x4){0.f, 0.f, 0.f, 0.f};

  int addr0[7];
#pragma unroll
  for (int t = 0; t < 7; ++t) {
    int p = mh * 112 + t * 16 + l15;   // 0..223
    int r = p / 56;
    int w = p - r * 56;
    addr0[t] = (r * 58 + w) * XSTR + kq * 8;
  }
  int woff[4];
#pragma unroll
  for (int i = 0; i < 4; ++i) woff[i] = (nh * 64 + i * 16 + l15) * WSTR + kq * 8;

  const ushort* xb = xh + (size_t)b * 58 * 58 * 128;
  const ushort* wb = Weff + (size_t)e * 9 * KN_ * C_;

  for (int cc = 0; cc < 4; ++cc) {
    const int c0 = cc * 32;
    __syncthreads();   // previous cc's sX reads complete
    // stage sX: 6 rows x 58 cols x 4 sub-chunks of 16 B
    for (int l = tid; l < 1392; l += 256) {
      int row = l / 232;
      int rem = l - row * 232;
      int col = rem >> 2, sub = rem & 3;
      uint4 v = *(const uint4*)(xb + ((size_t)(h0 + row) * 58 + col) * 128 + c0 + sub * 8);
      *(uint4*)&sX[(row * 58 + col) * XSTR + sub * 8] = v;
    }
    for (int dy = 0; dy < 3; ++dy) {
      __syncthreads();  // sX visible (dy=0) / previous sW reads complete
      {
        int l = tid;
#pragma unroll
        for (int it = 0; it < 6; ++it, l += 256) {   // 1536 chunks
          int sub = l & 3, o = (l >> 2) & 127, dx = l >> 9;
          uint4 v = *(const uint4*)(wb + (size_t)((dy * 3 + dx) * KN_ + o) * C_ + c0 + sub * 8);
          *(uint4*)&sW[(dx * 128 + o) * WSTR + sub * 8] = v;
        }
      }
      __syncthreads();
#pragma unroll
      for (int dx = 0; dx < 3; ++dx) {
        short8 bfr[4];
#pragma unroll
        for (int i = 0; i < 4; ++i)
          bfr[i] = *(const short8*)&sW[woff[i] + dx * 128 * WSTR];
        const int ao = (dy * 58 + dx) * XSTR;
#pragma unroll
        for (int t = 0; t < 7; ++t) {
          short8 a = *(const short8*)&sX[addr0[t] + ao];
#pragma unroll
          for (int i = 0; i < 4; ++i)
            acc[t][i] = __builtin_amdgcn_mfma_f32_16x16x32_bf16(a, bfr[i], acc[t][i], 0, 0, 0);
        }
      }
    }
  }

  // epilogue: lane rows p = mh*112 + t*16 + kq*4 + reg; col o = nh*64 + i*16 + l15
#pragma unroll
  for (int t = 0; t < 7; ++t) {
    int p0 = mh * 112 + t * 16 + kq * 4;
    int r  = p0 / 56;
    int w0 = p0 - r * 56;
    int h  = h0 + r;
#pragma unroll
    for (int i = 0; i < 4; ++i) {
      int o = nh * 64 + i * 16 + l15;
      float* op = out + (((size_t)bg * C_ + o) * H_ + h) * W_ + w0;
      *(float4*)op = make_float4(acc[t][i][0], acc[t][i][1], acc[t][i][2], acc[t][i][3]);
    }
  }
}

extern "C" void kernel_launch(void* const* d_in, const int* in_sizes, int n_in,
                              void* d_out, int out_size, void* d_ws, size_t ws_size,
                              hipStream_t stream) {
  const float* x    = (const float*)d_in[0];   // [32,128,56,56]
  const int*   gate = (const int*)d_in[1];     // [32,2]
  const float* Ws   = (const float*)d_in[2];   // [8,128,128,3,3]
  const float* Wch  = (const float*)d_in[3];   // [8,128,256,1,1]
  float* out = (float*)d_out;                  // [32,2,128,56,56]

  ushort* xh   = (ushort*)d_ws;                        // 32*58*58*128 bf16 = 27.56 MB
  ushort* Weff = xh + (size_t)32 * 58 * 58 * 128;      // [8][9][128][128] bf16 = 2.36 MB

  dim3 g0(58, 32);
  prep_x_kernel<<<g0, 256, 0, stream>>>(x, xh);

  dim3 g1(8, 4, 4);
  fuse_weights_kernel<<<g1, 256, 0, stream>>>(Ws, Wch, Weff);

  dim3 g2(14, 64);
  conv_mfma_kernel<<<g2, 256, 0, stream>>>(xh, gate, Weff, out);
}